// Round 17
// baseline (1281.848 us; speedup 1.0000x reference)
//
#include <hip/hip_runtime.h>
#include <math.h>

#define NTAU 82
#define TMIN 28
#define S_TOT 5617
#define TF 6000
#define BATCH 4
#define WMAX 28
#define AP 84            // fb row pitch (82 + 2 pad)
#define LPO 48           // A_lds row pitch: own parity block only
#define GP 96            // Ah global row pitch: 2 parity blocks x 48
#define NTHREADS 1024
#define NCHUNK 215
#define CHUNK_G (WMAX * GP)   // 2688 floats per chunk of A-history
#define NPOS 41          // own tempo blocks per half (block = 2*pos + h)
#define FLAG_STRIDE 64   // one flag per 256B line

// ws layout (float offsets)
#define TRANS_OFF 0            // 82*82
#define BLP_OFF   8192         // 4*6000
#define NBLP_OFF  32768        // 4*6000
#define AH_OFF    57344        // 4 * 215 * 2688 (parity-split A history + exchange)
#define FLAG_OFF  (AH_OFF + BATCH * NCHUNK * CHUNK_G)   // 8 flags x 64 ints
#define RESV_OFF  (FLAG_OFF + 8 * FLAG_STRIDE)          // 8 floats
#define RESI_OFF  (RESV_OFF + 8)                        // 8 ints

typedef float v2f __attribute__((ext_vector_type(2)));

__device__ __forceinline__ int first_of(int b) { return b * (55 + b) / 2; }

__device__ __forceinline__ float logsig(float x) {
    return -(fmaxf(-x, 0.0f) + log1pf(expf(-fabsf(x))));
}

// ---------------- setup kernel 1: trans_log in fp64, cast to fp32 -------------
__global__ void k_trans(float* __restrict__ ws) {
    int i = blockIdx.x;
    int j = threadIdx.x;
    __shared__ double sh[128];
    double raw = 0.0, e = 0.0;
    double ti = 28.0 + (double)i;
    if (j < NTAU) {
        double tj = 28.0 + (double)j;
        raw = -100.0 * fabs(tj / ti - 1.0);
        e = exp(raw);
    }
    sh[j] = e;
    __syncthreads();
    for (int st = 64; st > 0; st >>= 1) {
        if (j < st) sh[j] += sh[j + st];
        __syncthreads();
    }
    double lse = log(sh[0]);
    if (j < NTAU) ws[TRANS_OFF + i * NTAU + j] = (float)(raw - lse);
}

// ---------------- setup kernel 2: emissions + zero output ---------------------
__global__ void k_emis(const float* __restrict__ logit, float* __restrict__ ws,
                       float* __restrict__ out) {
    int idx = blockIdx.x * blockDim.x + threadIdx.x;
    if (idx < BATCH * TF) {
        float x = logit[idx];
        ws[BLP_OFF + idx]  = logsig(x);
        ws[NBLP_OFF + idx] = logsig(-x);
        out[idx] = 0.0f;
    }
}

// ---------------- setup kernel 3: zero the handshake flags --------------------
__global__ void k_flags(int* __restrict__ flags) {
    int i = blockIdx.x * blockDim.x + threadIdx.x;
    if (i < 8 * FLAG_STRIDE) flags[i] = 0;
}

// ------------- setup kernel 4: poison Ah pad cols (p=41..47) to -1e30 --------
__global__ void k_ahpad(float* __restrict__ Ah) {
    int i = blockIdx.x * blockDim.x + threadIdx.x;
    const int total = BATCH * NCHUNK * WMAX * 2 * 7;
    if (i < total) {
        int c7 = i % 7; int rest = i / 7;
        int par = rest & 1; rest >>= 1;
        int row = rest % WMAX; rest /= WMAX;
        int chunk = rest % NCHUNK; int bb = rest / NCHUNK;
        Ah[(size_t)bb * NCHUNK * CHUNK_G + (size_t)chunk * CHUNK_G
           + row * GP + par * 48 + 41 + c7] = -1.0e30f;
    }
}

// ---------------- main kernel: 2 CUs per batch, split by block parity ---------
// r16 base; ONLY change: ph2b reads partner operands DIRECTLY from global AhC
// (plain cached float4 — lines are L3-resident via partner's write-through
// atomics; our L2 never holds stale copies since chunk addresses are
// first-touch). Import step + barrier B3 deleted (5 -> 4 barriers/chunk).
__global__ __attribute__((amdgpu_flat_work_group_size(NTHREADS, NTHREADS),
                          amdgpu_waves_per_eu(4, 4),
                          amdgpu_num_vgpr(128)))
void k_viterbi(const float* __restrict__ logit,
               const float* __restrict__ transg,
               const float* __restrict__ blp_all,
               const float* __restrict__ nblp_all,
               float* __restrict__ Ah_all,
               int*   __restrict__ flags,
               float* __restrict__ resv,
               int*   __restrict__ resi,
               float* __restrict__ out) {
    const int tid = threadIdx.x;
    const int b   = blockIdx.x >> 1;   // batch
    const int h   = blockIdx.x & 1;    // half: owns tempo blocks 2*pos + h

    const float* blp  = blp_all  + b * TF;
    const float* nblp = nblp_all + b * TF;
    float* Ah = Ah_all + (size_t)b * (NCHUNK * CHUNK_G);
    int* flagOut = flags + (b * 2 + h) * FLAG_STRIDE;
    int* flagIn  = flags + (b * 2 + (1 - h)) * FLAG_STRIDE;

    __shared__ float V[2832];                         // own slots
    __shared__ __align__(16) float A_lds[WMAX * LPO]; // own-parity capture rows
    __shared__ __align__(16) float fb[WMAX * AP];     // from_beat, own cols
    __shared__ __align__(16) float win_nb[4][WMAX];
    __shared__ __align__(16) float win_b[4][WMAX];
    __shared__ float wv[16];
    __shared__ int   wi[16];
    __shared__ int   sstate;

    // ---- ph2 mapping: quad lanes = iseg (p-range); jpp = own j-pair; tg (12) ----
    const int iseg = tid & 3;
    const int jpp  = (tid >> 2) % 21;     // own cols j0 = 4*jpp+h, j1 = 4*jpp+2+h
    const int tg   = tid / 84;            // 0..11 (quads never straddle)
    const bool p2act = (tid < 1008);
    const int p0s = iseg * 12;            // parity-position range [p0s, p0s+12)
    const int j0 = 4 * jpp + h;
    const bool j1v = (jpp < 20);
    const int j1 = j1v ? (4 * jpp + 2 + h) : j0;

    // trans in regs, split by i-parity: own rows i=2p+h, partner i=2p+1-h
    float trO0[12], trO1[12], trP0[12], trP1[12];
#pragma unroll
    for (int k = 0; k < 12; ++k) {
        trO0[k] = -1.0e30f; trO1[k] = -1.0e30f;
        trP0[k] = -1.0e30f; trP1[k] = -1.0e30f;
    }
    if (p2act) {
#pragma unroll
        for (int k = 0; k < 12; ++k) {
            const int p = p0s + k;
            if (p <= 40) {
                const int iO = 2 * p + h, iP = 2 * p + 1 - h;
                trO0[k] = transg[iO * NTAU + j0];
                trP0[k] = transg[iP * NTAU + j0];
                if (j1v) {
                    trO1[k] = transg[iO * NTAU + j1];
                    trP1[k] = transg[iP * NTAU + j1];
                }
            }
        }
    }

    // ---- reset mapping: thread = (off o, base sp); own positions sp, sp+36 ----
    const bool ract = (tid < 1008);       // 28*36
    const int ro = ract ? (tid / 36) : 27;
    const int sp = tid % 36;
    const bool rv2 = ract && (sp < 5);
    const int pA = sp, pB = sp + 36;
    const int tauA = 28 + 2 * pA + h, tauB = 28 + 2 * pB + h;
    const int foA = pA * (27 + pA + h), foB = pB * (27 + pB + h);
    int rrA = ro, rrB = ro;

    // ---- non-reset mapping: flat f over own 1640/1681, 2 static slots ----
    const int NF_TOT = NPOS * (NPOS - 1 + h);
    int nrR[2], nrFo[2], nrTau[2];
    bool nrV[2];
#pragma unroll
    for (int q = 0; q < 2; ++q) {
        const int f = tid + q * NTHREADS;
        nrV[q] = (f < NF_TOT);
        nrR[q] = 28; nrFo[q] = 0; nrTau[q] = 109;
        if (nrV[q]) {
            int lo = 0, hi = NPOS - 1;
            while (lo < hi) { int mid = (lo + hi + 1) >> 1;
                              if (mid * (mid - 1 + h) <= f) lo = mid; else hi = mid - 1; }
            const int m = f - lo * (lo - 1 + h);
            nrR[q]   = TMIN + m;
            nrFo[q]  = lo * (27 + lo + h);
            nrTau[q] = TMIN + 2 * lo + h;
        }
    }

    // ---- V init (own slots) ----
    const float logS = (float)log((double)S_TOT);
    const float b0 = blp[0], n0 = nblp[0];
    const int SOWN = NPOS * (68 + h);
    for (int g = tid; g < SOWN; g += NTHREADS) {
        int lo = 0, hi = NPOS - 1;
        while (lo < hi) { int mid = (lo + hi + 1) >> 1;
                          if (mid * (27 + mid + h) <= g) lo = mid; else hi = mid - 1; }
        const int tau = TMIN + 2 * lo + h;
        const int r = g - lo * (27 + lo + h);
        V[g] = ((r == tau - 1) ? b0 : n0) - logS;
    }

    // A_lds: init ALL to -1e30 once; own cells (p<=40) rewritten every chunk;
    // pads p=41..47 persist for ph2a's iseg=3 tail reads.
    for (int idx = tid; idx < WMAX * LPO; idx += NTHREADS) A_lds[idx] = -1.0e30f;

    auto winload = [&](int cc) {
        if (cc < NCHUNK && tid < WMAX) {
            int gt = 1 + cc * WMAX + tid;
            win_nb[cc & 3][tid] = (gt < TF) ? nblp[gt] : 0.0f;
            win_b [cc & 3][tid] = (gt < TF) ? blp[gt]  : 0.0f;
        }
    };
    winload(0);
    winload(1);
    __syncthreads();

#define PH2P(av, aw, t0a, t0b, t1a, t1b) { \
    float x0 = (av) + (t0a); float y0 = (aw) + (t0b); \
    m0 = fmaxf(fmaxf(m0, x0), y0); \
    float x1 = (av) + (t1a); float y1 = (aw) + (t1b); \
    m1 = fmaxf(fmaxf(m1, x1), y1); }

    float cvA = 0.0f, cvB = 0.0f;
    float pm0[3], pm1[3];
    for (int c = 0; c < NCHUNK; ++c) {
        const int buf = c & 3;
        float* AhC = Ah + (size_t)c * CHUNK_G;

        // ---- prefix: capture C = V + nb[0..ro-1]; LDS + L3-coherent publish ----
        cvA = ract ? V[foA + rrA] : 0.0f;
        cvB = rv2  ? V[foB + rrB] : 0.0f;
        for (int tt = 0; tt < ro; ++tt) {
            const float w = win_nb[buf][tt];
            cvA += w; cvB += w;
        }
        if (ract) {
            A_lds[ro * LPO + pA] = cvA;
            __hip_atomic_store(&AhC[ro * GP + h * 48 + pA], cvA,
                               __ATOMIC_RELAXED, __HIP_MEMORY_SCOPE_AGENT);
            if (rv2) {
                A_lds[ro * LPO + pB] = cvB;
                __hip_atomic_store(&AhC[ro * GP + h * 48 + pB], cvB,
                                   __ATOMIC_RELAXED, __HIP_MEMORY_SCOPE_AGENT);
            }
        }
        winload(c + 2);
        __syncthreads();   // B1: own captures in LDS; publishes complete at L3

        // flag store: ordered after data by B1's vmcnt drain
        if (tid == 0)
            __hip_atomic_store(flagOut, c + 1, __ATOMIC_RELAXED, __HIP_MEMORY_SCOPE_AGENT);

        // ---- ph2a: OWN-parity max-plus half (local data) — hides exchange ----
        if (p2act) {
#pragma unroll
            for (int u = 0; u < 3; ++u) {
                const int tl = tg + 12 * u;
                float m0 = -INFINITY, m1 = -INFINITY;
                if (tl < WMAX) {
                    const float4* ar4 = (const float4*)&A_lds[tl * LPO + p0s];
                    const float4 a0 = ar4[0], a1 = ar4[1], a2 = ar4[2];
                    PH2P(a0.x, a0.y, trO0[0], trO0[1], trO1[0], trO1[1])
                    PH2P(a0.z, a0.w, trO0[2], trO0[3], trO1[2], trO1[3])
                    PH2P(a1.x, a1.y, trO0[4], trO0[5], trO1[4], trO1[5])
                    PH2P(a1.z, a1.w, trO0[6], trO0[7], trO1[6], trO1[7])
                    PH2P(a2.x, a2.y, trO0[8], trO0[9], trO1[8], trO1[9])
                    PH2P(a2.z, a2.w, trO0[10], trO0[11], trO1[10], trO1[11])
                }
                pm0[u] = m0; pm1[u] = m1;
            }
        }

        // ---- non-reset slots: 28 sequential pk adds (win_nb broadcast) ----
        {
            const int a0 = nrFo[0] + nrR[0];
            const int a1 = nrV[1] ? (nrFo[1] + nrR[1]) : a0;
            v2f v01 = v2f{V[a0], V[a1]};
#pragma unroll
            for (int tt = 0; tt < WMAX; ++tt) {
                const float w = win_nb[buf][tt];
                v01 += v2f{w, w};
            }
            V[a0] = v01.x;
            if (nrV[1]) V[a1] = v01.y;
        }

        // ---- wait for partner's chunk-c publishes (relaxed poll) ----
        if (tid == 0) {
            int guard = 0;
            while (__hip_atomic_load(flagIn, __ATOMIC_RELAXED, __HIP_MEMORY_SCOPE_AGENT) < c + 1) {
                __builtin_amdgcn_s_sleep(1);
                if (++guard > (1 << 24)) break;   // hang guard -> visible failure
            }
        }
        __syncthreads();   // B2: partner data in L3 (first-touch lines for us)

        // ---- ph2b: PARTNER-parity half read DIRECTLY from global; merge ----
        if (p2act) {
#pragma unroll
            for (int u = 0; u < 3; ++u) {
                const int tl = tg + 12 * u;
                if (tl < WMAX) {
                    const float4* ar4 =
                        (const float4*)&AhC[tl * GP + (1 - h) * 48 + p0s];
                    const float4 a0 = ar4[0], a1 = ar4[1], a2 = ar4[2];
                    float m0 = pm0[u], m1 = pm1[u];
                    PH2P(a0.x, a0.y, trP0[0], trP0[1], trP1[0], trP1[1])
                    PH2P(a0.z, a0.w, trP0[2], trP0[3], trP1[2], trP1[3])
                    PH2P(a1.x, a1.y, trP0[4], trP0[5], trP1[4], trP1[5])
                    PH2P(a1.z, a1.w, trP0[6], trP0[7], trP1[6], trP1[7])
                    PH2P(a2.x, a2.y, trP0[8], trP0[9], trP1[8], trP1[9])
                    PH2P(a2.z, a2.w, trP0[10], trP0[11], trP1[10], trP1[11])
                    m0 = fmaxf(m0, __shfl_xor(m0, 1)); m1 = fmaxf(m1, __shfl_xor(m1, 1));
                    m0 = fmaxf(m0, __shfl_xor(m0, 2)); m1 = fmaxf(m1, __shfl_xor(m1, 2));
                    if (iseg == 0) {
                        fb[tl * AP + j0] = m0;
                        if (j1v) fb[tl * AP + j1] = m1;
                    }
                }
            }
        }
        __syncthreads();   // B4: fb own cols ready

        // ---- suffix: entry + remaining adds (exact sequential) ----
        {
            const int colA = 2 * pA + h, colB = 2 * pB + h;
            const float bw = win_b[buf][ro];
            float eA = ract ? (fb[ro * AP + colA] + bw) : 0.0f;
            float eB = rv2  ? (fb[ro * AP + colB] + bw) : 0.0f;
            for (int tt = ro + 1; tt < WMAX; ++tt) {
                const float w = win_nb[buf][tt];
                eA += w; eB += w;
            }
            // last chunk (real width 7): resets at ro>=7 must not happen;
            // capture C == exact final value there (pad adds are +0.0)
            const bool keepC = (c == NCHUNK - 1) && (ro >= 7);
            if (ract) {
                V[foA + rrA] = keepC ? cvA : eA;
                if (rv2) V[foB + rrB] = keepC ? cvB : eB;
            }
            rrA += WMAX; if (rrA >= tauA) rrA -= tauA;
            rrB += WMAX; if (rrB >= tauB) rrB -= tauB;
        }
#pragma unroll
        for (int q = 0; q < 2; ++q) {
            if (nrV[q]) { nrR[q] += WMAX; if (nrR[q] >= nrTau[q]) nrR[q] -= nrTau[q]; }
        }
        __syncthreads();   // B5: protect V writes from next chunk's prefix reads
    }
#undef PH2P

    // ---- final argmax over OWN V (p = (5998 - r) mod tau; global state idx) ----
    float bvv = -INFINITY; int bss = 0x7fffffff;
    for (int g = tid; g < SOWN; g += NTHREADS) {
        int lo = 0, hi = NPOS - 1;
        while (lo < hi) { int mid = (lo + hi + 1) >> 1;
                          if (mid * (27 + mid + h) <= g) lo = mid; else hi = mid - 1; }
        const int tau = TMIN + 2 * lo + h;
        const int r = g - lo * (27 + lo + h);
        const int p = (5998 - r) % tau;
        const int s = first_of(2 * lo + h) + p;
        const float v = V[g];
        if (v > bvv || (v == bvv && s < bss)) { bvv = v; bss = s; }
    }
#pragma unroll
    for (int d = 1; d < 64; d <<= 1) {
        float ov = __shfl_xor(bvv, d);
        int   os = __shfl_xor(bss, d);
        if (ov > bvv || (ov == bvv && os < bss)) { bvv = ov; bss = os; }
    }
    if ((tid & 63) == 0) { wv[tid >> 6] = bvv; wi[tid >> 6] = bss; }
    __syncthreads();

    if (tid == 0) {
        float bv = wv[0]; int bs = wi[0];
#pragma unroll
        for (int k = 1; k < 16; ++k) {
            if (wv[k] > bv || (wv[k] == bv && wi[k] < bs)) { bv = wv[k]; bs = wi[k]; }
        }
        resv[b * 2 + h] = bv;
        resi[b * 2 + h] = bs;
        __hip_atomic_fetch_add(flagOut, 1, __ATOMIC_RELEASE, __HIP_MEMORY_SCOPE_AGENT);
        wv[0] = bv; wi[0] = bs;
    }
    if (h == 1) return;          // half 1 done; half 0 backtraces
    __syncthreads();

    if (tid == 0) {
        int guard = 0;
        while (__hip_atomic_load(flagIn, __ATOMIC_RELAXED, __HIP_MEMORY_SCOPE_AGENT) < NCHUNK + 1) {
            __builtin_amdgcn_s_sleep(1);
            if (++guard > (1 << 26)) break;
        }
        int fv = __hip_atomic_load(flagIn, __ATOMIC_ACQUIRE, __HIP_MEMORY_SCOPE_AGENT);
        if (fv == -0x7fffffff) wv[1] = -1.0e30f;   // unreachable; pins the acquire
        float bv = wv[0]; int bs = wi[0];
        const float pv = resv[b * 2 + 1];
        const int   ps = resi[b * 2 + 1];
        if (pv > bv || (pv == bv && ps < bs)) { bv = pv; bs = ps; }
        sstate = bs;
    }
    __syncthreads();

    // ---- backtrace: wave 0; Ah offset = (i&1)*48 + (i>>1) in parity layout ----
    if (tid < 64) {
        const int lane = tid;
        int s = sstate;
        int t = TF - 1;
        for (int guard = 0; guard < 400; ++guard) {
            int lo = 0, hi = NTAU - 1;
            while (lo < hi) { int mid = (lo + hi + 1) >> 1;
                              if (first_of(mid) <= s) lo = mid; else hi = mid - 1; }
            int j = lo;
            int p = s - first_of(j);
            int tb = t - p;
            if (tb < 0) break;
            if (lane == 0) {
                float x = logit[b * TF + tb];
                float act = 1.0f / (1.0f + expf(-x));
                if (act >= 0.05f) out[b * TF + tb] = 1.0f;
            }
            if (tb == 0) break;
            const int tq = tb - 1;
            const float* arow = Ah + (size_t)(tq / WMAX) * CHUNK_G + (tq % WMAX) * GP;
            float cvv = arow[(lane & 1) * 48 + (lane >> 1)] + transg[lane * NTAU + j];
            int ci = lane;
            if (lane < NTAU - 64) {
                const int i2 = 64 + lane;
                float c2 = arow[(i2 & 1) * 48 + (i2 >> 1)] + transg[i2 * NTAU + j];
                if (c2 > cvv) { cvv = c2; ci = i2; }
            }
#pragma unroll
            for (int d = 1; d < 64; d <<= 1) {
                float ov = __shfl_xor(cvv, d, 64);
                int   oi = __shfl_xor(ci, d, 64);
                if (ov > cvv || (ov == cvv && oi < ci)) { cvv = ov; ci = oi; }
            }
            s = first_of(ci) + (TMIN + ci) - 1;   // last_idx[i*]
            t = tb - 1;
        }
    }
}

extern "C" void kernel_launch(void* const* d_in, const int* in_sizes, int n_in,
                              void* d_out, int out_size, void* d_ws, size_t ws_size,
                              hipStream_t stream) {
    const float* logit = (const float*)d_in[0];
    float* out = (float*)d_out;
    float* ws = (float*)d_ws;
    k_trans<<<dim3(NTAU), dim3(128), 0, stream>>>(ws);
    k_emis<<<dim3((BATCH * TF + 255) / 256), dim3(256), 0, stream>>>(logit, ws, out);
    k_flags<<<dim3(2), dim3(256), 0, stream>>>((int*)(ws + FLAG_OFF));
    k_ahpad<<<dim3((BATCH * NCHUNK * WMAX * 2 * 7 + 255) / 256), dim3(256), 0, stream>>>(ws + AH_OFF);
    k_viterbi<<<dim3(BATCH * 2), dim3(NTHREADS), 0, stream>>>(
        logit, ws + TRANS_OFF, ws + BLP_OFF, ws + NBLP_OFF, ws + AH_OFF,
        (int*)(ws + FLAG_OFF), ws + RESV_OFF, (int*)(ws + RESI_OFF), out);
}

// Round 18
// 1240.922 us; speedup vs baseline: 1.0330x; 1.0330x over previous
//
#include <hip/hip_runtime.h>
#include <math.h>

#define NTAU 82
#define TMIN 28
#define S_TOT 5617
#define TF 6000
#define BATCH 4
#define WMAX 28
#define AP 84            // fb row pitch (82 + 2 pad)
#define LP 96            // A_lds row pitch: 2 parity blocks x 48
#define GP 88            // Ah global row pitch: 2 parity blocks x 44
#define NTHREADS 1024
#define NCHUNK 215
#define CHUNK_G (WMAX * GP)   // 2464 floats per chunk of A-history
#define NPOS 41          // own tempo blocks per half (block = 2*pos + h)
#define FLAG_STRIDE 64   // one flag per 256B line

// ws layout (float offsets)
#define TRANS_OFF 0            // 82*82
#define BLP_OFF   8192         // 4*6000
#define NBLP_OFF  32768        // 4*6000
#define AH_OFF    57344        // 4 * 215 * 2464 (parity-split A history + exchange)
#define FLAG_OFF  (AH_OFF + BATCH * NCHUNK * CHUNK_G)   // 8 flags x 64 ints
#define RESV_OFF  (FLAG_OFF + 8 * FLAG_STRIDE)          // 8 floats
#define RESI_OFF  (RESV_OFF + 8)                        // 8 ints

typedef float v2f __attribute__((ext_vector_type(2)));

__device__ __forceinline__ int first_of(int b) { return b * (55 + b) / 2; }

__device__ __forceinline__ float logsig(float x) {
    return -(fmaxf(-x, 0.0f) + log1pf(expf(-fabsf(x))));
}

// ---------------- setup kernel 1: trans_log in fp64, cast to fp32 -------------
__global__ void k_trans(float* __restrict__ ws) {
    int i = blockIdx.x;
    int j = threadIdx.x;
    __shared__ double sh[128];
    double raw = 0.0, e = 0.0;
    double ti = 28.0 + (double)i;
    if (j < NTAU) {
        double tj = 28.0 + (double)j;
        raw = -100.0 * fabs(tj / ti - 1.0);
        e = exp(raw);
    }
    sh[j] = e;
    __syncthreads();
    for (int st = 64; st > 0; st >>= 1) {
        if (j < st) sh[j] += sh[j + st];
        __syncthreads();
    }
    double lse = log(sh[0]);
    if (j < NTAU) ws[TRANS_OFF + i * NTAU + j] = (float)(raw - lse);
}

// ---------------- setup kernel 2: emissions + zero output ---------------------
__global__ void k_emis(const float* __restrict__ logit, float* __restrict__ ws,
                       float* __restrict__ out) {
    int idx = blockIdx.x * blockDim.x + threadIdx.x;
    if (idx < BATCH * TF) {
        float x = logit[idx];
        ws[BLP_OFF + idx]  = logsig(x);
        ws[NBLP_OFF + idx] = logsig(-x);
        out[idx] = 0.0f;
    }
}

// ---------------- setup kernel 3: zero the handshake flags --------------------
__global__ void k_flags(int* __restrict__ flags) {
    int i = blockIdx.x * blockDim.x + threadIdx.x;
    if (i < 8 * FLAG_STRIDE) flags[i] = 0;
}

// ------------- setup kernel 4: poison Ah pad cols (p=41..43) to -1e30 --------
__global__ void k_ahpad(float* __restrict__ Ah) {
    int i = blockIdx.x * blockDim.x + threadIdx.x;
    const int total = BATCH * NCHUNK * WMAX * 2 * 3;
    if (i < total) {
        int c3 = i % 3; int rest = i / 3;
        int par = rest & 1; rest >>= 1;
        int row = rest % WMAX; rest /= WMAX;
        int chunk = rest % NCHUNK; int bb = rest / NCHUNK;
        Ah[(size_t)bb * NCHUNK * CHUNK_G + (size_t)chunk * CHUNK_G
           + row * GP + par * 44 + 41 + c3] = -1.0e30f;
    }
}

// ---------------- main kernel: 2 CUs per batch, split by block parity ---------
// Champion structure (r16): parity-split A layout; ph2a (own-parity max-plus
// half) runs BETWEEN flag-store and poll — hides the exchange RT; ph2b
// (partner half) after coalesced float4 LDS import. Relaxed agent-scope
// atomics for exchange (no per-chunk wbL2/invL2). Max associative => exact.
__global__ __attribute__((amdgpu_flat_work_group_size(NTHREADS, NTHREADS),
                          amdgpu_waves_per_eu(4, 4),
                          amdgpu_num_vgpr(128)))
void k_viterbi(const float* __restrict__ logit,
               const float* __restrict__ transg,
               const float* __restrict__ blp_all,
               const float* __restrict__ nblp_all,
               float* __restrict__ Ah_all,
               int*   __restrict__ flags,
               float* __restrict__ resv,
               int*   __restrict__ resi,
               float* __restrict__ out) {
    const int tid = threadIdx.x;
    const int b   = blockIdx.x >> 1;   // batch
    const int h   = blockIdx.x & 1;    // half: owns tempo blocks 2*pos + h

    const float* blp  = blp_all  + b * TF;
    const float* nblp = nblp_all + b * TF;
    float* Ah = Ah_all + (size_t)b * (NCHUNK * CHUNK_G);
    int* flagOut = flags + (b * 2 + h) * FLAG_STRIDE;
    int* flagIn  = flags + (b * 2 + (1 - h)) * FLAG_STRIDE;

    __shared__ float V[2832];                        // own slots
    __shared__ __align__(16) float A_lds[WMAX * LP]; // parity-split capture rows
    __shared__ __align__(16) float fb[CHUNK_G];      // from_beat, own cols (AP pitch)
    __shared__ __align__(16) float win_nb[4][WMAX];
    __shared__ __align__(16) float win_b[4][WMAX];
    __shared__ float wv[16];
    __shared__ int   wi[16];
    __shared__ int   sstate;

    // ---- ph2 mapping: quad lanes = iseg (p-range); jpp = own j-pair; tg (12) ----
    const int iseg = tid & 3;
    const int jpp  = (tid >> 2) % 21;     // own cols j0 = 4*jpp+h, j1 = 4*jpp+2+h
    const int tg   = tid / 84;            // 0..11 (quads never straddle)
    const bool p2act = (tid < 1008);
    const int p0s = iseg * 12;            // parity-position range [p0s, p0s+12)
    const int j0 = 4 * jpp + h;
    const bool j1v = (jpp < 20);
    const int j1 = j1v ? (4 * jpp + 2 + h) : j0;

    // trans in regs, split by i-parity: own rows i=2p+h, partner i=2p+1-h
    float trO0[12], trO1[12], trP0[12], trP1[12];
#pragma unroll
    for (int k = 0; k < 12; ++k) {
        trO0[k] = -1.0e30f; trO1[k] = -1.0e30f;
        trP0[k] = -1.0e30f; trP1[k] = -1.0e30f;
    }
    if (p2act) {
#pragma unroll
        for (int k = 0; k < 12; ++k) {
            const int p = p0s + k;
            if (p <= 40) {
                const int iO = 2 * p + h, iP = 2 * p + 1 - h;
                trO0[k] = transg[iO * NTAU + j0];
                trP0[k] = transg[iP * NTAU + j0];
                if (j1v) {
                    trO1[k] = transg[iO * NTAU + j1];
                    trP1[k] = transg[iP * NTAU + j1];
                }
            }
        }
    }

    // ---- reset mapping: thread = (off o, base sp); own positions sp, sp+36 ----
    const bool ract = (tid < 1008);       // 28*36
    const int ro = ract ? (tid / 36) : 27;
    const int sp = tid % 36;
    const bool rv2 = ract && (sp < 5);
    const int pA = sp, pB = sp + 36;
    const int tauA = 28 + 2 * pA + h, tauB = 28 + 2 * pB + h;
    const int foA = pA * (27 + pA + h), foB = pB * (27 + pB + h);
    int rrA = ro, rrB = ro;

    // ---- non-reset mapping: flat f over own 1640/1681, 2 static slots ----
    const int NF_TOT = NPOS * (NPOS - 1 + h);
    int nrR[2], nrFo[2], nrTau[2];
    bool nrV[2];
#pragma unroll
    for (int q = 0; q < 2; ++q) {
        const int f = tid + q * NTHREADS;
        nrV[q] = (f < NF_TOT);
        nrR[q] = 28; nrFo[q] = 0; nrTau[q] = 109;
        if (nrV[q]) {
            int lo = 0, hi = NPOS - 1;
            while (lo < hi) { int mid = (lo + hi + 1) >> 1;
                              if (mid * (mid - 1 + h) <= f) lo = mid; else hi = mid - 1; }
            const int m = f - lo * (lo - 1 + h);
            nrR[q]   = TMIN + m;
            nrFo[q]  = lo * (27 + lo + h);
            nrTau[q] = TMIN + 2 * lo + h;
        }
    }

    // ---- V init (own slots) ----
    const float logS = (float)log((double)S_TOT);
    const float b0 = blp[0], n0 = nblp[0];
    const int SOWN = NPOS * (68 + h);
    for (int g = tid; g < SOWN; g += NTHREADS) {
        int lo = 0, hi = NPOS - 1;
        while (lo < hi) { int mid = (lo + hi + 1) >> 1;
                          if (mid * (27 + mid + h) <= g) lo = mid; else hi = mid - 1; }
        const int tau = TMIN + 2 * lo + h;
        const int r = g - lo * (27 + lo + h);
        V[g] = ((r == tau - 1) ? b0 : n0) - logS;
    }

    // A_lds: init ALL to -1e30 once; real cells rewritten every chunk
    // (own p<=40 by prefix, partner p<=43 by import); pads persist.
    for (int idx = tid; idx < WMAX * LP; idx += NTHREADS) A_lds[idx] = -1.0e30f;

    auto winload = [&](int cc) {
        if (cc < NCHUNK && tid < WMAX) {
            int gt = 1 + cc * WMAX + tid;
            win_nb[cc & 3][tid] = (gt < TF) ? nblp[gt] : 0.0f;
            win_b [cc & 3][tid] = (gt < TF) ? blp[gt]  : 0.0f;
        }
    };
    winload(0);
    winload(1);
    __syncthreads();

#define PH2P(av, aw, t0a, t0b, t1a, t1b) { \
    float x0 = (av) + (t0a); float y0 = (aw) + (t0b); \
    m0 = fmaxf(fmaxf(m0, x0), y0); \
    float x1 = (av) + (t1a); float y1 = (aw) + (t1b); \
    m1 = fmaxf(fmaxf(m1, x1), y1); }

    float cvA = 0.0f, cvB = 0.0f;
    float pm0[3], pm1[3];
    for (int c = 0; c < NCHUNK; ++c) {
        const int buf = c & 3;
        float* AhC = Ah + (size_t)c * CHUNK_G;

        // ---- prefix: capture C = V + nb[0..ro-1]; LDS + L3-coherent publish ----
        cvA = ract ? V[foA + rrA] : 0.0f;
        cvB = rv2  ? V[foB + rrB] : 0.0f;
        for (int tt = 0; tt < ro; ++tt) {
            const float w = win_nb[buf][tt];
            cvA += w; cvB += w;
        }
        if (ract) {
            A_lds[ro * LP + h * 48 + pA] = cvA;
            __hip_atomic_store(&AhC[ro * GP + h * 44 + pA], cvA,
                               __ATOMIC_RELAXED, __HIP_MEMORY_SCOPE_AGENT);
            if (rv2) {
                A_lds[ro * LP + h * 48 + pB] = cvB;
                __hip_atomic_store(&AhC[ro * GP + h * 44 + pB], cvB,
                                   __ATOMIC_RELAXED, __HIP_MEMORY_SCOPE_AGENT);
            }
        }
        winload(c + 2);
        __syncthreads();   // B1: own captures in LDS; publishes complete at L3

        // flag store: ordered after data by B1's vmcnt drain
        if (tid == 0)
            __hip_atomic_store(flagOut, c + 1, __ATOMIC_RELAXED, __HIP_MEMORY_SCOPE_AGENT);

        // ---- ph2a: OWN-parity max-plus half (local data) — hides exchange ----
        if (p2act) {
#pragma unroll
            for (int u = 0; u < 3; ++u) {
                const int tl = tg + 12 * u;
                float m0 = -INFINITY, m1 = -INFINITY;
                if (tl < WMAX) {
                    const float4* ar4 = (const float4*)&A_lds[tl * LP + h * 48 + p0s];
                    const float4 a0 = ar4[0], a1 = ar4[1], a2 = ar4[2];
                    PH2P(a0.x, a0.y, trO0[0], trO0[1], trO1[0], trO1[1])
                    PH2P(a0.z, a0.w, trO0[2], trO0[3], trO1[2], trO1[3])
                    PH2P(a1.x, a1.y, trO0[4], trO0[5], trO1[4], trO1[5])
                    PH2P(a1.z, a1.w, trO0[6], trO0[7], trO1[6], trO1[7])
                    PH2P(a2.x, a2.y, trO0[8], trO0[9], trO1[8], trO1[9])
                    PH2P(a2.z, a2.w, trO0[10], trO0[11], trO1[10], trO1[11])
                }
                pm0[u] = m0; pm1[u] = m1;
            }
        }

        // ---- non-reset slots: 28 sequential pk adds (win_nb broadcast) ----
        {
            const int a0 = nrFo[0] + nrR[0];
            const int a1 = nrV[1] ? (nrFo[1] + nrR[1]) : a0;
            v2f v01 = v2f{V[a0], V[a1]};
#pragma unroll
            for (int tt = 0; tt < WMAX; ++tt) {
                const float w = win_nb[buf][tt];
                v01 += v2f{w, w};
            }
            V[a0] = v01.x;
            if (nrV[1]) V[a1] = v01.y;
        }

        // ---- wait for partner's chunk-c publishes (relaxed poll) ----
        if (tid == 0) {
            int guard = 0;
            while (__hip_atomic_load(flagIn, __ATOMIC_RELAXED, __HIP_MEMORY_SCOPE_AGENT) < c + 1) {
                __builtin_amdgcn_s_sleep(1);
                if (++guard > (1 << 24)) break;   // hang guard -> visible failure
            }
        }
        __syncthreads();   // B2: partner data in L3

        // ---- import partner parity block: coalesced float4 (first-touch lines) --
        if (tid < 308) {
            const int row = tid / 11, s4 = tid % 11;
            const float4 v4 = *(const float4*)&AhC[row * GP + (1 - h) * 44 + s4 * 4];
            *(float4*)&A_lds[row * LP + (1 - h) * 48 + s4 * 4] = v4;
        }
        __syncthreads();   // B3: full parity-split rows ready

        // ---- ph2b: PARTNER-parity half; merge; quad-reduce; write fb ----
        if (p2act) {
#pragma unroll
            for (int u = 0; u < 3; ++u) {
                const int tl = tg + 12 * u;
                if (tl < WMAX) {
                    const float4* ar4 = (const float4*)&A_lds[tl * LP + (1 - h) * 48 + p0s];
                    const float4 a0 = ar4[0], a1 = ar4[1], a2 = ar4[2];
                    float m0 = pm0[u], m1 = pm1[u];
                    PH2P(a0.x, a0.y, trP0[0], trP0[1], trP1[0], trP1[1])
                    PH2P(a0.z, a0.w, trP0[2], trP0[3], trP1[2], trP1[3])
                    PH2P(a1.x, a1.y, trP0[4], trP0[5], trP1[4], trP1[5])
                    PH2P(a1.z, a1.w, trP0[6], trP0[7], trP1[6], trP1[7])
                    PH2P(a2.x, a2.y, trP0[8], trP0[9], trP1[8], trP1[9])
                    PH2P(a2.z, a2.w, trP0[10], trP0[11], trP1[10], trP1[11])
                    m0 = fmaxf(m0, __shfl_xor(m0, 1)); m1 = fmaxf(m1, __shfl_xor(m1, 1));
                    m0 = fmaxf(m0, __shfl_xor(m0, 2)); m1 = fmaxf(m1, __shfl_xor(m1, 2));
                    if (iseg == 0) {
                        fb[tl * AP + j0] = m0;
                        if (j1v) fb[tl * AP + j1] = m1;
                    }
                }
            }
        }
        __syncthreads();   // B4: fb own cols ready

        // ---- suffix: entry + remaining adds (exact sequential) ----
        {
            const int colA = 2 * pA + h, colB = 2 * pB + h;
            const float bw = win_b[buf][ro];
            float eA = ract ? (fb[ro * AP + colA] + bw) : 0.0f;
            float eB = rv2  ? (fb[ro * AP + colB] + bw) : 0.0f;
            for (int tt = ro + 1; tt < WMAX; ++tt) {
                const float w = win_nb[buf][tt];
                eA += w; eB += w;
            }
            // last chunk (real width 7): resets at ro>=7 must not happen;
            // capture C == exact final value there (pad adds are +0.0)
            const bool keepC = (c == NCHUNK - 1) && (ro >= 7);
            if (ract) {
                V[foA + rrA] = keepC ? cvA : eA;
                if (rv2) V[foB + rrB] = keepC ? cvB : eB;
            }
            rrA += WMAX; if (rrA >= tauA) rrA -= tauA;
            rrB += WMAX; if (rrB >= tauB) rrB -= tauB;
        }
#pragma unroll
        for (int q = 0; q < 2; ++q) {
            if (nrV[q]) { nrR[q] += WMAX; if (nrR[q] >= nrTau[q]) nrR[q] -= nrTau[q]; }
        }
        __syncthreads();   // B5: protect V writes from next chunk's prefix reads
    }
#undef PH2P

    // ---- final argmax over OWN V (p = (5998 - r) mod tau; global state idx) ----
    float bvv = -INFINITY; int bss = 0x7fffffff;
    for (int g = tid; g < SOWN; g += NTHREADS) {
        int lo = 0, hi = NPOS - 1;
        while (lo < hi) { int mid = (lo + hi + 1) >> 1;
                          if (mid * (27 + mid + h) <= g) lo = mid; else hi = mid - 1; }
        const int tau = TMIN + 2 * lo + h;
        const int r = g - lo * (27 + lo + h);
        const int p = (5998 - r) % tau;
        const int s = first_of(2 * lo + h) + p;
        const float v = V[g];
        if (v > bvv || (v == bvv && s < bss)) { bvv = v; bss = s; }
    }
#pragma unroll
    for (int d = 1; d < 64; d <<= 1) {
        float ov = __shfl_xor(bvv, d);
        int   os = __shfl_xor(bss, d);
        if (ov > bvv || (ov == bvv && os < bss)) { bvv = ov; bss = os; }
    }
    if ((tid & 63) == 0) { wv[tid >> 6] = bvv; wi[tid >> 6] = bss; }
    __syncthreads();

    if (tid == 0) {
        float bv = wv[0]; int bs = wi[0];
#pragma unroll
        for (int k = 1; k < 16; ++k) {
            if (wv[k] > bv || (wv[k] == bv && wi[k] < bs)) { bv = wv[k]; bs = wi[k]; }
        }
        resv[b * 2 + h] = bv;
        resi[b * 2 + h] = bs;
        __hip_atomic_fetch_add(flagOut, 1, __ATOMIC_RELEASE, __HIP_MEMORY_SCOPE_AGENT);
        wv[0] = bv; wi[0] = bs;
    }
    if (h == 1) return;          // half 1 done; half 0 backtraces
    __syncthreads();

    if (tid == 0) {
        int guard = 0;
        while (__hip_atomic_load(flagIn, __ATOMIC_RELAXED, __HIP_MEMORY_SCOPE_AGENT) < NCHUNK + 1) {
            __builtin_amdgcn_s_sleep(1);
            if (++guard > (1 << 26)) break;
        }
        int fv = __hip_atomic_load(flagIn, __ATOMIC_ACQUIRE, __HIP_MEMORY_SCOPE_AGENT);
        if (fv == -0x7fffffff) wv[1] = -1.0e30f;   // unreachable; pins the acquire
        float bv = wv[0]; int bs = wi[0];
        const float pv = resv[b * 2 + 1];
        const int   ps = resi[b * 2 + 1];
        if (pv > bv || (pv == bv && ps < bs)) { bv = pv; bs = ps; }
        sstate = bs;
    }
    __syncthreads();

    // ---- backtrace: wave 0; Ah offset = (i&1)*44 + (i>>1) in parity layout ----
    if (tid < 64) {
        const int lane = tid;
        int s = sstate;
        int t = TF - 1;
        for (int guard = 0; guard < 400; ++guard) {
            int lo = 0, hi = NTAU - 1;
            while (lo < hi) { int mid = (lo + hi + 1) >> 1;
                              if (first_of(mid) <= s) lo = mid; else hi = mid - 1; }
            int j = lo;
            int p = s - first_of(j);
            int tb = t - p;
            if (tb < 0) break;
            if (lane == 0) {
                float x = logit[b * TF + tb];
                float act = 1.0f / (1.0f + expf(-x));
                if (act >= 0.05f) out[b * TF + tb] = 1.0f;
            }
            if (tb == 0) break;
            const int tq = tb - 1;
            const float* arow = Ah + (size_t)(tq / WMAX) * CHUNK_G + (tq % WMAX) * GP;
            float cvv = arow[(lane & 1) * 44 + (lane >> 1)] + transg[lane * NTAU + j];
            int ci = lane;
            if (lane < NTAU - 64) {
                const int i2 = 64 + lane;
                float c2 = arow[(i2 & 1) * 44 + (i2 >> 1)] + transg[i2 * NTAU + j];
                if (c2 > cvv) { cvv = c2; ci = i2; }
            }
#pragma unroll
            for (int d = 1; d < 64; d <<= 1) {
                float ov = __shfl_xor(cvv, d, 64);
                int   oi = __shfl_xor(ci, d, 64);
                if (ov > cvv || (ov == cvv && oi < ci)) { cvv = ov; ci = oi; }
            }
            s = first_of(ci) + (TMIN + ci) - 1;   // last_idx[i*]
            t = tb - 1;
        }
    }
}

extern "C" void kernel_launch(void* const* d_in, const int* in_sizes, int n_in,
                              void* d_out, int out_size, void* d_ws, size_t ws_size,
                              hipStream_t stream) {
    const float* logit = (const float*)d_in[0];
    float* out = (float*)d_out;
    float* ws = (float*)d_ws;
    k_trans<<<dim3(NTAU), dim3(128), 0, stream>>>(ws);
    k_emis<<<dim3((BATCH * TF + 255) / 256), dim3(256), 0, stream>>>(logit, ws, out);
    k_flags<<<dim3(2), dim3(256), 0, stream>>>((int*)(ws + FLAG_OFF));
    k_ahpad<<<dim3((BATCH * NCHUNK * WMAX * 2 * 3 + 255) / 256), dim3(256), 0, stream>>>(ws + AH_OFF);
    k_viterbi<<<dim3(BATCH * 2), dim3(NTHREADS), 0, stream>>>(
        logit, ws + TRANS_OFF, ws + BLP_OFF, ws + NBLP_OFF, ws + AH_OFF,
        (int*)(ws + FLAG_OFF), ws + RESV_OFF, (int*)(ws + RESI_OFF), out);
}